// Round 1
// baseline (475.160 us; speedup 1.0000x reference)
//
#include <hip/hip_runtime.h>

// NCE / NT-Xent loss, N=4096, D=256, fp32.
// W = [normalize(x1); normalize(x2)]  (2N x D), logits(r,j) = 10*W[r].W[j], j != r.
// loss[r] = log( sum_{j!=r} exp(10*W[r].W[j] - 10) ) + 10 - 10*W[r].W[partner(r)]
// Fixed shift of 10 is exact enough: dots in [-1,1] -> exp arg in [-20, 0].

#define N_ROWS 4096
#define D      256
#define TWO_N  8192
#define INV_T  10.0f

#define BQ 64          // query tile
#define BK 128         // key tile
#define DC 32          // depth chunk staged in LDS
#define KSPLIT 8       // key-dimension split for parallelism
#define KEYS_PER_WG (TWO_N / KSPLIT)   // 1024

// ---------------- normalize: one wave per row ----------------
__global__ __launch_bounds__(256) void normalize_k(const float* __restrict__ x1,
                                                   const float* __restrict__ x2,
                                                   float* __restrict__ W) {
    int row  = (int)((blockIdx.x * blockDim.x + threadIdx.x) >> 6);
    int lane = threadIdx.x & 63;
    const float* src = (row < N_ROWS) ? (x1 + (size_t)row * D)
                                      : (x2 + (size_t)(row - N_ROWS) * D);
    float4 v = ((const float4*)src)[lane];          // 64 lanes * 4 floats = 256
    float ss = v.x * v.x + v.y * v.y + v.z * v.z + v.w * v.w;
    #pragma unroll
    for (int off = 32; off > 0; off >>= 1) ss += __shfl_xor(ss, off);
    float scale = 1.0f / fmaxf(sqrtf(ss), 1e-8f);   // torch CosineSimilarity eps clamp
    float4 o = make_float4(v.x * scale, v.y * scale, v.z * scale, v.w * scale);
    ((float4*)(W + (size_t)row * D))[lane] = o;
}

// ---------------- main: fused Gram tile + sum-of-exp ----------------
// Grid: (TWO_N/BQ, KSPLIT) x 256 threads. Micro-tile per thread: 8 queries x 4 keys.
__global__ __launch_bounds__(256) void nce_partial_k(const float* __restrict__ W,
                                                     float* __restrict__ S) {
    __shared__ float Alds[DC][BQ];   // d-major: Alds[d][q]
    __shared__ float Blds[DC][BK];   // d-major: Blds[d][k]

    const int tid = threadIdx.x;
    const int tq  = tid & 7;    // 8 query-groups of 8
    const int tk  = tid >> 3;   // 32 key-groups of 4
    const int q0  = blockIdx.x * BQ;
    const int kbase = blockIdx.y * KEYS_PER_WG;

    float psum[8] = {0.f,0.f,0.f,0.f,0.f,0.f,0.f,0.f};

    for (int kt = 0; kt < KEYS_PER_WG / BK; ++kt) {
        const int k0 = kbase + kt * BK;
        float acc[8][4];
        #pragma unroll
        for (int i = 0; i < 8; ++i)
            #pragma unroll
            for (int j = 0; j < 4; ++j) acc[i][j] = 0.f;

        for (int dc = 0; dc < D; dc += DC) {
            __syncthreads();
            {   // stage A tile (BQ x DC), transposed into Alds[d][q].
                // r = lane-distinct row -> LDS write bank = r%32, 2-way max (free).
                int r = tid & 63, c = (tid >> 6) * 8;
                const float* src = W + (size_t)(q0 + r) * D + dc + c;
                float4 a0 = ((const float4*)src)[0];
                float4 a1 = ((const float4*)src)[1];
                Alds[c+0][r]=a0.x; Alds[c+1][r]=a0.y; Alds[c+2][r]=a0.z; Alds[c+3][r]=a0.w;
                Alds[c+4][r]=a1.x; Alds[c+5][r]=a1.y; Alds[c+6][r]=a1.z; Alds[c+7][r]=a1.w;
            }
            {   // stage B tile (BK x DC), transposed into Blds[d][k].
                int r = tid & 127, c = (tid >> 7) * 16;
                const float* src = W + (size_t)(k0 + r) * D + dc + c;
                float4 b0 = ((const float4*)src)[0];
                float4 b1 = ((const float4*)src)[1];
                float4 b2 = ((const float4*)src)[2];
                float4 b3 = ((const float4*)src)[3];
                Blds[c+ 0][r]=b0.x; Blds[c+ 1][r]=b0.y; Blds[c+ 2][r]=b0.z; Blds[c+ 3][r]=b0.w;
                Blds[c+ 4][r]=b1.x; Blds[c+ 5][r]=b1.y; Blds[c+ 6][r]=b1.z; Blds[c+ 7][r]=b1.w;
                Blds[c+ 8][r]=b2.x; Blds[c+ 9][r]=b2.y; Blds[c+10][r]=b2.z; Blds[c+11][r]=b2.w;
                Blds[c+12][r]=b3.x; Blds[c+13][r]=b3.y; Blds[c+14][r]=b3.z; Blds[c+15][r]=b3.w;
            }
            __syncthreads();

            #pragma unroll
            for (int d = 0; d < DC; ++d) {
                float a[8], b[4];
                *(float4*)(a)     = *(const float4*)&Alds[d][tq * 8];      // 32B aligned
                *(float4*)(a + 4) = *(const float4*)&Alds[d][tq * 8 + 4];
                *(float4*)(b)     = *(const float4*)&Blds[d][tk * 4];      // 16B aligned
                #pragma unroll
                for (int i = 0; i < 8; ++i)
                    #pragma unroll
                    for (int j = 0; j < 4; ++j)
                        acc[i][j] = fmaf(a[i], b[j], acc[i][j]);
            }
        }

        // exp + accumulate, masking the self pair (sim11/sim22 diagonal).
        #pragma unroll
        for (int i = 0; i < 8; ++i) {
            int qg = q0 + tq * 8 + i;
            #pragma unroll
            for (int j = 0; j < 4; ++j) {
                int kg = k0 + tk * 4 + j;
                if (kg != qg) psum[i] += __expf(INV_T * acc[i][j] - 10.0f);
            }
        }
    }

    // Reduce over tk within the wave (tq lives in lane bits 0..2).
    #pragma unroll
    for (int off = 8; off < 64; off <<= 1)
        #pragma unroll
        for (int i = 0; i < 8; ++i) psum[i] += __shfl_xor(psum[i], off);

    __syncthreads();
    float* red = &Alds[0][0];           // reuse LDS: 4 waves x 64 queries
    int wv = tid >> 6;
    if ((tid & 63) < 8) {
        #pragma unroll
        for (int i = 0; i < 8; ++i) red[wv * 64 + tq * 8 + i] = psum[i];
    }
    __syncthreads();
    if (tid < 64) {
        float s = red[tid] + red[64 + tid] + red[128 + tid] + red[192 + tid];
        atomicAdd(&S[q0 + tid], s);     // KSPLIT partial adds per row total
    }
}

// ---------------- final: loss = log(S) + 10 - 10*pos ----------------
__global__ __launch_bounds__(256) void nce_final_k(const float* __restrict__ W,
                                                   const float* __restrict__ S,
                                                   float* __restrict__ out) {
    int row  = (int)((blockIdx.x * blockDim.x + threadIdx.x) >> 6);
    int lane = threadIdx.x & 63;
    int partner = (row < N_ROWS) ? row + N_ROWS : row - N_ROWS;
    float4 a = ((const float4*)(W + (size_t)row * D))[lane];
    float4 b = ((const float4*)(W + (size_t)partner * D))[lane];
    float d = a.x * b.x + a.y * b.y + a.z * b.z + a.w * b.w;
    #pragma unroll
    for (int off = 32; off > 0; off >>= 1) d += __shfl_xor(d, off);
    if (lane == 0) out[row] = logf(S[row]) + 10.0f - INV_T * d;
}

extern "C" void kernel_launch(void* const* d_in, const int* in_sizes, int n_in,
                              void* d_out, int out_size, void* d_ws, size_t ws_size,
                              hipStream_t stream) {
    const float* x1 = (const float*)d_in[0];
    const float* x2 = (const float*)d_in[1];
    float* out = (float*)d_out;

    float* W = (float*)d_ws;                       // 8192*256 floats = 8 MB
    float* S = W + (size_t)TWO_N * D;              // 8192 floats (ws re-poisoned -> must zero)

    hipMemsetAsync(S, 0, TWO_N * sizeof(float), stream);
    normalize_k<<<TWO_N / 4, 256, 0, stream>>>(x1, x2, W);
    dim3 grid(TWO_N / BQ, KSPLIT);
    nce_partial_k<<<grid, 256, 0, stream>>>(W, S);
    nce_final_k<<<TWO_N / 4, 256, 0, stream>>>(W, S, out);
}

// Round 4
// 173.443 us; speedup vs baseline: 2.7396x; 2.7396x over previous
//
#include <hip/hip_runtime.h>

// NT-Xent / NCE loss via split-precision bf16 MFMA Gram matrix.
// W = [normalize(x1); normalize(x2)] (8192 x 256), decomposed W = Whi + Wlo (bf16 each).
// dot ~= hi.hi + hi.lo + lo.hi (3 MFMAs, fp32 accum; lo.lo ~ 2^-16 dropped).
// loss[r] = log( sum_{j!=r} exp(10*dot(r,j) - 10) ) + 10 - 10*dot(r, partner(r))

#define N_ROWS 4096
#define D      256
#define TWO_N  8192

typedef __attribute__((ext_vector_type(8))) short bf16x8;
typedef __attribute__((ext_vector_type(4))) float f32x4;

#define MFMA16(a, b, c) __builtin_amdgcn_mfma_f32_16x16x32_bf16((a), (b), (c), 0, 0, 0)

static __device__ __forceinline__ float bf2f(unsigned short b) {
    return __uint_as_float(((unsigned)b) << 16);
}
static __device__ __forceinline__ unsigned short f2bf(float x) {  // RNE
    unsigned u = __float_as_uint(x);
    return (unsigned short)((u + 0x7FFF + ((u >> 16) & 1)) >> 16);
}
static __device__ __forceinline__ void gload16(const void* g, void* l) {
    __builtin_amdgcn_global_load_lds((const __attribute__((address_space(1))) void*)g,
                                     (__attribute__((address_space(3))) void*)l, 16, 0, 0);
}

// ---------------- normalize + bf16 hi/lo split ----------------
__global__ __launch_bounds__(256) void normalize_k(const float* __restrict__ x1,
                                                   const float* __restrict__ x2,
                                                   unsigned short* __restrict__ Whi,
                                                   unsigned short* __restrict__ Wlo) {
    int row  = (int)((blockIdx.x * blockDim.x + threadIdx.x) >> 6);
    int lane = threadIdx.x & 63;
    const float* src = (row < N_ROWS) ? (x1 + (size_t)row * D)
                                      : (x2 + (size_t)(row - N_ROWS) * D);
    float4 v = ((const float4*)src)[lane];
    float ss = v.x * v.x + v.y * v.y + v.z * v.z + v.w * v.w;
    #pragma unroll
    for (int off = 32; off > 0; off >>= 1) ss += __shfl_xor(ss, off);
    float scale = 1.0f / fmaxf(sqrtf(ss), 1e-8f);
    float a[4] = {v.x * scale, v.y * scale, v.z * scale, v.w * scale};
    ushort4 h, l;
    unsigned short* hp = (unsigned short*)&h;
    unsigned short* lp = (unsigned short*)&l;
    #pragma unroll
    for (int i = 0; i < 4; ++i) {
        hp[i] = f2bf(a[i]);
        lp[i] = f2bf(a[i] - bf2f(hp[i]));
    }
    ((ushort4*)(Whi + (size_t)row * D))[lane] = h;
    ((ushort4*)(Wlo + (size_t)row * D))[lane] = l;
}

// ---------------- main: Gram tile via MFMA + fused exp-sum ----------------
// Grid: 4096 blocks (64x64 tile grid, XCD-swizzled), 256 threads = 4 waves (2x2).
// Per block: 128x128 output, K=256 in 8 chunks of BK=32.
// LDS granule (16B = 8 bf16) placement: slot(row,g) = row*4 + (g ^ ((row>>1)&3))
// -> ds_read_b128 fragment reads hit all 8 bank-groups per 8-lane phase (conflict-free).
__global__ __launch_bounds__(256, 2) void nce_partial_k(const unsigned short* __restrict__ Whi,
                                                        const unsigned short* __restrict__ Wlo,
                                                        float* __restrict__ S) {
    __shared__ unsigned short tile[4][4096];   // Ahi, Alo, Bhi, Blo: 128x32 bf16 each, swizzled
    __shared__ float Srow[128];

    const int tid  = threadIdx.x;
    const int wid  = tid >> 6, lane = tid & 63;
    const int lr   = lane & 15, lg = lane >> 4;
    const int wr   = wid >> 1,  wc = wid & 1;

    const int bid = blockIdx.x;
    const int swz = (bid & 7) * 512 + (bid >> 3);     // XCD-contiguous (4096 % 8 == 0)
    const int bi  = swz & 63, bj = swz >> 6;
    const int q0  = bi * 128, c0 = bj * 128;

    if (tid < 128) Srow[tid] = 0.f;

    f32x4 acc[4][4];
    #pragma unroll
    for (int i = 0; i < 4; ++i)
        #pragma unroll
        for (int j = 0; j < 4; ++j) acc[i][j] = (f32x4)0.f;

    // staging source offsets (pre-swizzled so LDS can stay linear)
    const int j0 = tid, j1 = tid + 256;
    const int r0 = j0 >> 2, g0 = (j0 & 3) ^ ((r0 >> 1) & 3);
    const int r1 = j1 >> 2, g1 = (j1 & 3) ^ ((r1 >> 1) & 3);
    const size_t soff0 = (size_t)r0 * D + g0 * 8;
    const size_t soff1 = (size_t)r1 * D + g1 * 8;
    const unsigned short* srcAh = Whi + (size_t)q0 * D;
    const unsigned short* srcAl = Wlo + (size_t)q0 * D;
    const unsigned short* srcBh = Whi + (size_t)c0 * D;
    const unsigned short* srcBl = Wlo + (size_t)c0 * D;
    const unsigned db0 = (unsigned)(tid & ~63) * 16u;          // wave-uniform LDS byte base
    const unsigned db1 = db0 + 256u * 16u;

    // fragment LDS byte offsets (per-lane, constant across chunks)
    int offA[4], offB[4];
    #pragma unroll
    for (int s = 0; s < 4; ++s) {
        int rowA = wr * 64 + s * 16 + lr;
        int rowB = wc * 64 + s * 16 + lr;
        int x = lg ^ ((lr >> 1) & 3);
        offA[s] = (rowA * 4 + x) * 16;
        offB[s] = (rowB * 4 + x) * 16;
    }

    for (int kc = 0; kc < D; kc += 32) {
        __syncthreads();   // previous chunk's reads done -> LDS reusable
        gload16(srcAh + soff0 + kc, (char*)&tile[0][0] + db0);
        gload16(srcAh + soff1 + kc, (char*)&tile[0][0] + db1);
        gload16(srcAl + soff0 + kc, (char*)&tile[1][0] + db0);
        gload16(srcAl + soff1 + kc, (char*)&tile[1][0] + db1);
        gload16(srcBh + soff0 + kc, (char*)&tile[2][0] + db0);
        gload16(srcBh + soff1 + kc, (char*)&tile[2][0] + db1);
        gload16(srcBl + soff0 + kc, (char*)&tile[3][0] + db0);
        gload16(srcBl + soff1 + kc, (char*)&tile[3][0] + db1);
        __syncthreads();   // compiler drains vmcnt before s_barrier

        bf16x8 bh[4], bl[4];
        #pragma unroll
        for (int sj = 0; sj < 4; ++sj) {
            bh[sj] = *(const bf16x8*)((const char*)&tile[2][0] + offB[sj]);
            bl[sj] = *(const bf16x8*)((const char*)&tile[3][0] + offB[sj]);
        }
        #pragma unroll
        for (int si = 0; si < 4; ++si) {
            bf16x8 ah = *(const bf16x8*)((const char*)&tile[0][0] + offA[si]);
            bf16x8 al = *(const bf16x8*)((const char*)&tile[1][0] + offA[si]);
            #pragma unroll
            for (int sj = 0; sj < 4; ++sj) {
                acc[si][sj] = MFMA16(ah, bh[sj], acc[si][sj]);
                acc[si][sj] = MFMA16(ah, bl[sj], acc[si][sj]);
                acc[si][sj] = MFMA16(al, bh[sj], acc[si][sj]);
            }
        }
    }

    // epilogue: exp + mask + row-sum.  C/D map: row=(lane>>4)*4+reg, col=lane&15
    float rs[4][4];
    #pragma unroll
    for (int si = 0; si < 4; ++si)
        #pragma unroll
        for (int r = 0; r < 4; ++r) rs[si][r] = 0.f;

    #pragma unroll
    for (int si = 0; si < 4; ++si) {
        int grb = q0 + wr * 64 + si * 16 + lg * 4;
        #pragma unroll
        for (int sj = 0; sj < 4; ++sj) {
            int gc = c0 + wc * 64 + sj * 16 + lr;
            #pragma unroll
            for (int r = 0; r < 4; ++r) {
                float e = __expf(fmaf(10.f, acc[si][sj][r], -10.f));
                rs[si][r] += (grb + r == gc) ? 0.f : e;
            }
        }
    }
    #pragma unroll
    for (int off = 1; off < 16; off <<= 1)
        #pragma unroll
        for (int si = 0; si < 4; ++si)
            #pragma unroll
            for (int r = 0; r < 4; ++r) rs[si][r] += __shfl_xor(rs[si][r], off);

    if (lr == 0) {
        #pragma unroll
        for (int si = 0; si < 4; ++si)
            #pragma unroll
            for (int r = 0; r < 4; ++r)
                atomicAdd(&Srow[wr * 64 + si * 16 + lg * 4 + r], rs[si][r]);
    }
    __syncthreads();
    if (tid < 128) atomicAdd(&S[q0 + tid], Srow[tid]);
}

// ---------------- final: loss = log(S) + 10 - 10*pos ----------------
__global__ __launch_bounds__(256) void nce_final_k(const unsigned short* __restrict__ Whi,
                                                   const unsigned short* __restrict__ Wlo,
                                                   const float* __restrict__ S,
                                                   float* __restrict__ out) {
    int row  = (int)((blockIdx.x * blockDim.x + threadIdx.x) >> 6);
    int lane = threadIdx.x & 63;
    int partner = (row < N_ROWS) ? row + N_ROWS : row - N_ROWS;
    ushort4 ah = ((const ushort4*)(Whi + (size_t)row * D))[lane];
    ushort4 al = ((const ushort4*)(Wlo + (size_t)row * D))[lane];
    ushort4 bh = ((const ushort4*)(Whi + (size_t)partner * D))[lane];
    ushort4 bl = ((const ushort4*)(Wlo + (size_t)partner * D))[lane];
    const unsigned short* ahp = (const unsigned short*)&ah;
    const unsigned short* alp = (const unsigned short*)&al;
    const unsigned short* bhp = (const unsigned short*)&bh;
    const unsigned short* blp = (const unsigned short*)&bl;
    float d = 0.f;
    #pragma unroll
    for (int i = 0; i < 4; ++i) {
        float a = bf2f(ahp[i]) + bf2f(alp[i]);
        float b = bf2f(bhp[i]) + bf2f(blp[i]);
        d = fmaf(a, b, d);
    }
    #pragma unroll
    for (int off = 32; off > 0; off >>= 1) d += __shfl_xor(d, off);
    if (lane == 0) out[row] = logf(S[row]) + 10.0f - 10.0f * d;
}

extern "C" void kernel_launch(void* const* d_in, const int* in_sizes, int n_in,
                              void* d_out, int out_size, void* d_ws, size_t ws_size,
                              hipStream_t stream) {
    const float* x1 = (const float*)d_in[0];
    const float* x2 = (const float*)d_in[1];
    float* out = (float*)d_out;

    unsigned short* Whi = (unsigned short*)d_ws;                    // 4 MB
    unsigned short* Wlo = Whi + (size_t)TWO_N * D;                  // 4 MB
    float* S = (float*)(Wlo + (size_t)TWO_N * D);                   // 32 KB

    hipMemsetAsync(S, 0, TWO_N * sizeof(float), stream);
    normalize_k<<<TWO_N / 4, 256, 0, stream>>>(x1, x2, Whi, Wlo);
    nce_partial_k<<<4096, 256, 0, stream>>>(Whi, Wlo, S);
    nce_final_k<<<TWO_N / 4, 256, 0, stream>>>(Whi, Wlo, S, out);
}

// Round 5
// 125.911 us; speedup vs baseline: 3.7738x; 1.3775x over previous
//
#include <hip/hip_runtime.h>

// NT-Xent / NCE loss via split-precision bf16 MFMA Gram matrix, symmetric half.
// W = [normalize(x1); normalize(x2)] (8192 x 256), decomposed W = Whi + Wlo (bf16 each).
// dot ~= hi.hi + hi.lo + lo.hi (3 MFMAs, fp32 accum; lo.lo ~ 2^-16 dropped).
// Gram is symmetric: compute upper-triangular 128x128 tiles only; each off-diag
// tile contributes exp row-sums to S[rows] AND col-sums to S[cols].
// loss[r] = log( sum_{j!=r} exp(10*dot(r,j) - 10) ) + 10 - 10*dot(r, partner(r))

#define N_ROWS 4096
#define D      256
#define TWO_N  8192
#define NTILE  64                    // 8192 / 128
#define NTRI   (NTILE * (NTILE + 1) / 2)   // 2080 triangular tiles

typedef __attribute__((ext_vector_type(8))) short bf16x8;
typedef __attribute__((ext_vector_type(4))) float f32x4;

#define MFMA16(a, b, c) __builtin_amdgcn_mfma_f32_16x16x32_bf16((a), (b), (c), 0, 0, 0)

static __device__ __forceinline__ float bf2f(unsigned short b) {
    return __uint_as_float(((unsigned)b) << 16);
}
static __device__ __forceinline__ unsigned short f2bf(float x) {  // RNE
    unsigned u = __float_as_uint(x);
    return (unsigned short)((u + 0x7FFF + ((u >> 16) & 1)) >> 16);
}
static __device__ __forceinline__ void gload16(const void* g, void* l) {
    __builtin_amdgcn_global_load_lds((const __attribute__((address_space(1))) void*)g,
                                     (__attribute__((address_space(3))) void*)l, 16, 0, 0);
}

// ---------------- normalize + bf16 hi/lo split (+ zero S) ----------------
__global__ __launch_bounds__(256) void normalize_k(const float* __restrict__ x1,
                                                   const float* __restrict__ x2,
                                                   unsigned short* __restrict__ Whi,
                                                   unsigned short* __restrict__ Wlo,
                                                   float* __restrict__ S) {
    if (blockIdx.x < 32) S[(blockIdx.x << 8) | threadIdx.x] = 0.f;   // 32*256 = 8192

    int row  = (int)((blockIdx.x * blockDim.x + threadIdx.x) >> 6);
    int lane = threadIdx.x & 63;
    const float* src = (row < N_ROWS) ? (x1 + (size_t)row * D)
                                      : (x2 + (size_t)(row - N_ROWS) * D);
    float4 v = ((const float4*)src)[lane];
    float ss = v.x * v.x + v.y * v.y + v.z * v.z + v.w * v.w;
    #pragma unroll
    for (int off = 32; off > 0; off >>= 1) ss += __shfl_xor(ss, off);
    float scale = 1.0f / fmaxf(sqrtf(ss), 1e-8f);
    float a[4] = {v.x * scale, v.y * scale, v.z * scale, v.w * scale};
    ushort4 h, l;
    unsigned short* hp = (unsigned short*)&h;
    unsigned short* lp = (unsigned short*)&l;
    #pragma unroll
    for (int i = 0; i < 4; ++i) {
        hp[i] = f2bf(a[i]);
        lp[i] = f2bf(a[i] - bf2f(hp[i]));
    }
    ((ushort4*)(Whi + (size_t)row * D))[lane] = h;
    ((ushort4*)(Wlo + (size_t)row * D))[lane] = l;
}

// ---------------- main: triangular Gram tiles + fused exp row/col sums ------
// Grid: 2080 blocks (upper-triangular 128x128 tiles, XCD-swizzled), 4 waves (2x2).
// LDS granule (16B = 8 bf16) placement: slot(row,g) = row*4 + (g ^ ((row>>1)&3))
// -> ds_read_b128 fragment reads hit all 8 bank-groups per 8-lane phase (conflict-free).
__global__ __launch_bounds__(256, 2) void nce_partial_k(const unsigned short* __restrict__ Whi,
                                                        const unsigned short* __restrict__ Wlo,
                                                        float* __restrict__ S) {
    __shared__ unsigned short tile[4][4096];   // Ahi, Alo, Bhi, Blo: 128x32 bf16, swizzled
    __shared__ float Srow[128];
    __shared__ float Scol[128];

    const int tid  = threadIdx.x;
    const int wid  = tid >> 6, lane = tid & 63;
    const int lr   = lane & 15, lg = lane >> 4;
    const int wr   = wid >> 1,  wc = wid & 1;

    // XCD-contiguous triangular tile id (NTRI = 2080, 2080 % 8 == 0 -> bijective)
    const int t = (blockIdx.x & 7) * (NTRI / 8) + (blockIdx.x >> 3);
    // decode t -> (bi <= bj): f(i) = 64i - i(i-1)/2 pairs precede row i
    #define FPC(i) ((i) * NTILE - (i) * ((i) - 1) / 2)
    int bi = (int)((129.0f - sqrtf((float)(129 * 129 - 8 * t))) * 0.5f);
    while (FPC(bi + 1) <= t) ++bi;
    while (FPC(bi) > t) --bi;
    const int bj = bi + (t - FPC(bi));
    const int q0 = bi * 128, c0 = bj * 128;
    const bool offdiag = (bi != bj);

    if (tid < 128) { Srow[tid] = 0.f; Scol[tid] = 0.f; }

    f32x4 acc[4][4];
    #pragma unroll
    for (int i = 0; i < 4; ++i)
        #pragma unroll
        for (int j = 0; j < 4; ++j) acc[i][j] = (f32x4)0.f;

    // staging source offsets (pre-swizzled so LDS dest stays linear; rule #21)
    const int j0 = tid, j1 = tid + 256;
    const int r0 = j0 >> 2, g0 = (j0 & 3) ^ ((r0 >> 1) & 3);
    const int r1 = j1 >> 2, g1 = (j1 & 3) ^ ((r1 >> 1) & 3);
    const size_t soff0 = (size_t)r0 * D + g0 * 8;
    const size_t soff1 = (size_t)r1 * D + g1 * 8;
    const unsigned short* srcAh = Whi + (size_t)q0 * D;
    const unsigned short* srcAl = Wlo + (size_t)q0 * D;
    const unsigned short* srcBh = Whi + (size_t)c0 * D;
    const unsigned short* srcBl = Wlo + (size_t)c0 * D;
    const unsigned db0 = (unsigned)(tid & ~63) * 16u;          // wave-uniform LDS byte base
    const unsigned db1 = db0 + 256u * 16u;

    // fragment LDS byte offsets (per-lane, constant across chunks)
    int offA[4], offB[4];
    #pragma unroll
    for (int s = 0; s < 4; ++s) {
        int rowA = wr * 64 + s * 16 + lr;
        int rowB = wc * 64 + s * 16 + lr;
        int x = lg ^ ((lr >> 1) & 3);
        offA[s] = (rowA * 4 + x) * 16;
        offB[s] = (rowB * 4 + x) * 16;
    }

    for (int kc = 0; kc < D; kc += 32) {
        __syncthreads();   // previous chunk's reads done -> LDS reusable
        gload16(srcAh + soff0 + kc, (char*)&tile[0][0] + db0);
        gload16(srcAh + soff1 + kc, (char*)&tile[0][0] + db1);
        gload16(srcAl + soff0 + kc, (char*)&tile[1][0] + db0);
        gload16(srcAl + soff1 + kc, (char*)&tile[1][0] + db1);
        gload16(srcBh + soff0 + kc, (char*)&tile[2][0] + db0);
        gload16(srcBh + soff1 + kc, (char*)&tile[2][0] + db1);
        gload16(srcBl + soff0 + kc, (char*)&tile[3][0] + db0);
        gload16(srcBl + soff1 + kc, (char*)&tile[3][0] + db1);
        __syncthreads();   // compiler drains vmcnt before s_barrier

        bf16x8 bh[4], bl[4];
        #pragma unroll
        for (int sj = 0; sj < 4; ++sj) {
            bh[sj] = *(const bf16x8*)((const char*)&tile[2][0] + offB[sj]);
            bl[sj] = *(const bf16x8*)((const char*)&tile[3][0] + offB[sj]);
        }
        #pragma unroll
        for (int si = 0; si < 4; ++si) {
            bf16x8 ah = *(const bf16x8*)((const char*)&tile[0][0] + offA[si]);
            bf16x8 al = *(const bf16x8*)((const char*)&tile[1][0] + offA[si]);
            #pragma unroll
            for (int sj = 0; sj < 4; ++sj) {
                acc[si][sj] = MFMA16(ah, bh[sj], acc[si][sj]);
                acc[si][sj] = MFMA16(ah, bl[sj], acc[si][sj]);
                acc[si][sj] = MFMA16(al, bh[sj], acc[si][sj]);
            }
        }
    }

    // epilogue: exp + self-mask; row-sums always, col-sums for off-diag tiles.
    // C/D map: row = (lane>>4)*4 + reg, col = lane&15
    float rs[4][4];
    float cs[4] = {0.f, 0.f, 0.f, 0.f};
    #pragma unroll
    for (int si = 0; si < 4; ++si)
        #pragma unroll
        for (int r = 0; r < 4; ++r) rs[si][r] = 0.f;

    #pragma unroll
    for (int si = 0; si < 4; ++si) {
        int grb = q0 + wr * 64 + si * 16 + lg * 4;
        #pragma unroll
        for (int sj = 0; sj < 4; ++sj) {
            int gc = c0 + wc * 64 + sj * 16 + lr;
            #pragma unroll
            for (int r = 0; r < 4; ++r) {
                float e = __expf(fmaf(10.f, acc[si][sj][r], -10.f));
                e = (grb + r == gc) ? 0.f : e;
                rs[si][r] += e;
                cs[sj]    += e;
            }
        }
    }
    // row reduce: sum over columns -> butterfly across lr (lane bits 0..3)
    #pragma unroll
    for (int off = 1; off < 16; off <<= 1)
        #pragma unroll
        for (int si = 0; si < 4; ++si)
            #pragma unroll
            for (int r = 0; r < 4; ++r) rs[si][r] += __shfl_xor(rs[si][r], off);
    if (lr == 0) {
        #pragma unroll
        for (int si = 0; si < 4; ++si)
            #pragma unroll
            for (int r = 0; r < 4; ++r)
                atomicAdd(&Srow[wr * 64 + si * 16 + lg * 4 + r], rs[si][r]);
    }
    // col reduce: sum over rows -> butterfly across lg (lane bits 4..5)
    if (offdiag) {
        #pragma unroll
        for (int sj = 0; sj < 4; ++sj) {
            cs[sj] += __shfl_xor(cs[sj], 16);
            cs[sj] += __shfl_xor(cs[sj], 32);
        }
        if (lg == 0) {
            #pragma unroll
            for (int sj = 0; sj < 4; ++sj)
                atomicAdd(&Scol[wc * 64 + sj * 16 + lr], cs[sj]);
        }
    }
    __syncthreads();
    if (tid < 128) {
        atomicAdd(&S[q0 + tid], Srow[tid]);
        if (offdiag) atomicAdd(&S[c0 + tid], Scol[tid]);
    }
}

// ---------------- final: loss = log(S) + 10 - 10*pos ----------------
__global__ __launch_bounds__(256) void nce_final_k(const unsigned short* __restrict__ Whi,
                                                   const unsigned short* __restrict__ Wlo,
                                                   const float* __restrict__ S,
                                                   float* __restrict__ out) {
    int row  = (int)((blockIdx.x * blockDim.x + threadIdx.x) >> 6);
    int lane = threadIdx.x & 63;
    int partner = (row < N_ROWS) ? row + N_ROWS : row - N_ROWS;
    ushort4 ah = ((const ushort4*)(Whi + (size_t)row * D))[lane];
    ushort4 al = ((const ushort4*)(Wlo + (size_t)row * D))[lane];
    ushort4 bh = ((const ushort4*)(Whi + (size_t)partner * D))[lane];
    ushort4 bl = ((const ushort4*)(Wlo + (size_t)partner * D))[lane];
    const unsigned short* ahp = (const unsigned short*)&ah;
    const unsigned short* alp = (const unsigned short*)&al;
    const unsigned short* bhp = (const unsigned short*)&bh;
    const unsigned short* blp = (const unsigned short*)&bl;
    float d = 0.f;
    #pragma unroll
    for (int i = 0; i < 4; ++i) {
        float a = bf2f(ahp[i]) + bf2f(alp[i]);
        float b = bf2f(bhp[i]) + bf2f(blp[i]);
        d = fmaf(a, b, d);
    }
    #pragma unroll
    for (int off = 32; off > 0; off >>= 1) d += __shfl_xor(d, off);
    if (lane == 0) out[row] = logf(S[row]) + 10.0f - 10.0f * d;
}

extern "C" void kernel_launch(void* const* d_in, const int* in_sizes, int n_in,
                              void* d_out, int out_size, void* d_ws, size_t ws_size,
                              hipStream_t stream) {
    const float* x1 = (const float*)d_in[0];
    const float* x2 = (const float*)d_in[1];
    float* out = (float*)d_out;

    unsigned short* Whi = (unsigned short*)d_ws;                    // 4 MB
    unsigned short* Wlo = Whi + (size_t)TWO_N * D;                  // 4 MB
    float* S = (float*)(Wlo + (size_t)TWO_N * D);                   // 32 KB

    normalize_k<<<TWO_N / 4, 256, 0, stream>>>(x1, x2, Whi, Wlo, S);
    nce_partial_k<<<NTRI, 256, 0, stream>>>(Whi, Wlo, S);
    nce_final_k<<<TWO_N / 4, 256, 0, stream>>>(Whi, Wlo, S, out);
}

// Round 6
// 123.916 us; speedup vs baseline: 3.8345x; 1.0161x over previous
//
#include <hip/hip_runtime.h>

// NT-Xent / NCE loss via split-precision bf16 MFMA Gram matrix, symmetric half.
// W = [normalize(x1); normalize(x2)] (8192 x 256), decomposed W = Whi + Wlo (bf16 each).
// dot ~= hi.hi + hi.lo + lo.hi (3 MFMAs, fp32 accum; lo.lo ~ 2^-16 dropped).
// Gram is symmetric: compute upper-triangular 128x128 tiles only; each off-diag
// tile contributes exp row-sums to S[rows] AND col-sums to S[cols].
// loss[r] = log( sum_{j!=r} exp(10*dot(r,j) - 10) ) + 10 - 10*dot(r, partner(r))

#define N_ROWS 4096
#define D      256
#define TWO_N  8192
#define NTILE  64                    // 8192 / 128
#define NTRI   (NTILE * (NTILE + 1) / 2)   // 2080 triangular tiles

typedef __attribute__((ext_vector_type(8))) short bf16x8;
typedef __attribute__((ext_vector_type(4))) float f32x4;

#define MFMA16(a, b, c) __builtin_amdgcn_mfma_f32_16x16x32_bf16((a), (b), (c), 0, 0, 0)

static __device__ __forceinline__ float bf2f(unsigned short b) {
    return __uint_as_float(((unsigned)b) << 16);
}
static __device__ __forceinline__ unsigned short f2bf(float x) {  // RNE
    unsigned u = __float_as_uint(x);
    return (unsigned short)((u + 0x7FFF + ((u >> 16) & 1)) >> 16);
}
static __device__ __forceinline__ void gload16(const void* g, void* l) {
    __builtin_amdgcn_global_load_lds((const __attribute__((address_space(1))) void*)g,
                                     (__attribute__((address_space(3))) void*)l, 16, 0, 0);
}

// ---------------- normalize + bf16 hi/lo split (+ zero S) ----------------
__global__ __launch_bounds__(256) void normalize_k(const float* __restrict__ x1,
                                                   const float* __restrict__ x2,
                                                   unsigned short* __restrict__ Whi,
                                                   unsigned short* __restrict__ Wlo,
                                                   float* __restrict__ S) {
    if (blockIdx.x < 32) S[(blockIdx.x << 8) | threadIdx.x] = 0.f;   // 32*256 = 8192

    int row  = (int)((blockIdx.x * blockDim.x + threadIdx.x) >> 6);
    int lane = threadIdx.x & 63;
    const float* src = (row < N_ROWS) ? (x1 + (size_t)row * D)
                                      : (x2 + (size_t)(row - N_ROWS) * D);
    float4 v = ((const float4*)src)[lane];
    float ss = v.x * v.x + v.y * v.y + v.z * v.z + v.w * v.w;
    #pragma unroll
    for (int off = 32; off > 0; off >>= 1) ss += __shfl_xor(ss, off);
    float scale = 1.0f / fmaxf(sqrtf(ss), 1e-8f);
    float a[4] = {v.x * scale, v.y * scale, v.z * scale, v.w * scale};
    ushort4 h, l;
    unsigned short* hp = (unsigned short*)&h;
    unsigned short* lp = (unsigned short*)&l;
    #pragma unroll
    for (int i = 0; i < 4; ++i) {
        hp[i] = f2bf(a[i]);
        lp[i] = f2bf(a[i] - bf2f(hp[i]));
    }
    ((ushort4*)(Whi + (size_t)row * D))[lane] = h;
    ((ushort4*)(Wlo + (size_t)row * D))[lane] = l;
}

// ---------------- main: triangular Gram tiles + fused exp row/col sums ------
// Grid: 2080 blocks (upper-triangular 128x128 tiles, XCD-swizzled), 4 waves (2x2).
// __launch_bounds__(256,3): ~140 unified regs/wave (76 VGPR + 64 AGPR acc) ->
// 3 waves/SIMD fits without spill; 3 blocks/CU gives cross-block overlap of the
// per-chunk vmcnt(0)+barrier drain (m114 mechanism). LDS 33 KB x 3 = 101 KB ok.
// LDS granule (16B = 8 bf16) placement: slot(row,g) = row*4 + (g ^ ((row>>1)&3))
// -> ds_read_b128 fragment reads hit all 8 bank-groups per 8-lane phase (conflict-free).
__global__ __launch_bounds__(256, 3) void nce_partial_k(const unsigned short* __restrict__ Whi,
                                                        const unsigned short* __restrict__ Wlo,
                                                        float* __restrict__ S) {
    __shared__ unsigned short tile[4][4096];   // Ahi, Alo, Bhi, Blo: 128x32 bf16, swizzled
    __shared__ float Srow[128];
    __shared__ float Scol[128];

    const int tid  = threadIdx.x;
    const int wid  = tid >> 6, lane = tid & 63;
    const int lr   = lane & 15, lg = lane >> 4;
    const int wr   = wid >> 1,  wc = wid & 1;

    // XCD-contiguous triangular tile id (NTRI = 2080, 2080 % 8 == 0 -> bijective)
    const int t = (blockIdx.x & 7) * (NTRI / 8) + (blockIdx.x >> 3);
    // decode t -> (bi <= bj): f(i) = 64i - i(i-1)/2 pairs precede row i
    #define FPC(i) ((i) * NTILE - (i) * ((i) - 1) / 2)
    int bi = (int)((129.0f - sqrtf((float)(129 * 129 - 8 * t))) * 0.5f);
    while (FPC(bi + 1) <= t) ++bi;
    while (FPC(bi) > t) --bi;
    const int bj = bi + (t - FPC(bi));
    const int q0 = bi * 128, c0 = bj * 128;
    const bool offdiag = (bi != bj);

    if (tid < 128) { Srow[tid] = 0.f; Scol[tid] = 0.f; }

    f32x4 acc[4][4];
    #pragma unroll
    for (int i = 0; i < 4; ++i)
        #pragma unroll
        for (int j = 0; j < 4; ++j) acc[i][j] = (f32x4)0.f;

    // staging source offsets (pre-swizzled so LDS dest stays linear; rule #21)
    const int j0 = tid, j1 = tid + 256;
    const int r0 = j0 >> 2, g0 = (j0 & 3) ^ ((r0 >> 1) & 3);
    const int r1 = j1 >> 2, g1 = (j1 & 3) ^ ((r1 >> 1) & 3);
    const size_t soff0 = (size_t)r0 * D + g0 * 8;
    const size_t soff1 = (size_t)r1 * D + g1 * 8;
    const unsigned short* srcAh = Whi + (size_t)q0 * D;
    const unsigned short* srcAl = Wlo + (size_t)q0 * D;
    const unsigned short* srcBh = Whi + (size_t)c0 * D;
    const unsigned short* srcBl = Wlo + (size_t)c0 * D;
    const unsigned db0 = (unsigned)(tid & ~63) * 16u;          // wave-uniform LDS byte base
    const unsigned db1 = db0 + 256u * 16u;

    // fragment LDS byte offsets (per-lane, constant across chunks)
    int offA[4], offB[4];
    #pragma unroll
    for (int s = 0; s < 4; ++s) {
        int rowA = wr * 64 + s * 16 + lr;
        int rowB = wc * 64 + s * 16 + lr;
        int x = lg ^ ((lr >> 1) & 3);
        offA[s] = (rowA * 4 + x) * 16;
        offB[s] = (rowB * 4 + x) * 16;
    }

    for (int kc = 0; kc < D; kc += 32) {
        __syncthreads();   // previous chunk's reads done -> LDS reusable
        gload16(srcAh + soff0 + kc, (char*)&tile[0][0] + db0);
        gload16(srcAh + soff1 + kc, (char*)&tile[0][0] + db1);
        gload16(srcAl + soff0 + kc, (char*)&tile[1][0] + db0);
        gload16(srcAl + soff1 + kc, (char*)&tile[1][0] + db1);
        gload16(srcBh + soff0 + kc, (char*)&tile[2][0] + db0);
        gload16(srcBh + soff1 + kc, (char*)&tile[2][0] + db1);
        gload16(srcBl + soff0 + kc, (char*)&tile[3][0] + db0);
        gload16(srcBl + soff1 + kc, (char*)&tile[3][0] + db1);
        __syncthreads();   // compiler drains vmcnt before s_barrier

        bf16x8 bh[4], bl[4];
        #pragma unroll
        for (int sj = 0; sj < 4; ++sj) {
            bh[sj] = *(const bf16x8*)((const char*)&tile[2][0] + offB[sj]);
            bl[sj] = *(const bf16x8*)((const char*)&tile[3][0] + offB[sj]);
        }
        #pragma unroll
        for (int si = 0; si < 4; ++si) {
            bf16x8 ah = *(const bf16x8*)((const char*)&tile[0][0] + offA[si]);
            bf16x8 al = *(const bf16x8*)((const char*)&tile[1][0] + offA[si]);
            #pragma unroll
            for (int sj = 0; sj < 4; ++sj) {
                acc[si][sj] = MFMA16(ah, bh[sj], acc[si][sj]);
                acc[si][sj] = MFMA16(ah, bl[sj], acc[si][sj]);
                acc[si][sj] = MFMA16(al, bh[sj], acc[si][sj]);
            }
        }
    }

    // epilogue: exp + self-mask; row-sums always, col-sums for off-diag tiles.
    // C/D map: row = (lane>>4)*4 + reg, col = lane&15
    float rs[4][4];
    float cs[4] = {0.f, 0.f, 0.f, 0.f};
    #pragma unroll
    for (int si = 0; si < 4; ++si)
        #pragma unroll
        for (int r = 0; r < 4; ++r) rs[si][r] = 0.f;

    #pragma unroll
    for (int si = 0; si < 4; ++si) {
        int grb = q0 + wr * 64 + si * 16 + lg * 4;
        #pragma unroll
        for (int sj = 0; sj < 4; ++sj) {
            int gc = c0 + wc * 64 + sj * 16 + lr;
            #pragma unroll
            for (int r = 0; r < 4; ++r) {
                float e = __expf(fmaf(10.f, acc[si][sj][r], -10.f));
                e = (grb + r == gc) ? 0.f : e;
                rs[si][r] += e;
                cs[sj]    += e;
            }
        }
    }
    // row reduce: sum over columns -> butterfly across lr (lane bits 0..3)
    #pragma unroll
    for (int off = 1; off < 16; off <<= 1)
        #pragma unroll
        for (int si = 0; si < 4; ++si)
            #pragma unroll
            for (int r = 0; r < 4; ++r) rs[si][r] += __shfl_xor(rs[si][r], off);
    if (lr == 0) {
        #pragma unroll
        for (int si = 0; si < 4; ++si)
            #pragma unroll
            for (int r = 0; r < 4; ++r)
                atomicAdd(&Srow[wr * 64 + si * 16 + lg * 4 + r], rs[si][r]);
    }
    // col reduce: sum over rows -> butterfly across lg (lane bits 4..5)
    if (offdiag) {
        #pragma unroll
        for (int sj = 0; sj < 4; ++sj) {
            cs[sj] += __shfl_xor(cs[sj], 16);
            cs[sj] += __shfl_xor(cs[sj], 32);
        }
        if (lg == 0) {
            #pragma unroll
            for (int sj = 0; sj < 4; ++sj)
                atomicAdd(&Scol[wc * 64 + sj * 16 + lr], cs[sj]);
        }
    }
    __syncthreads();
    if (tid < 128) {
        atomicAdd(&S[q0 + tid], Srow[tid]);
        if (offdiag) atomicAdd(&S[c0 + tid], Scol[tid]);
    }
}

// ---------------- final: loss = log(S) + 10 - 10*pos ----------------
__global__ __launch_bounds__(256) void nce_final_k(const unsigned short* __restrict__ Whi,
                                                   const unsigned short* __restrict__ Wlo,
                                                   const float* __restrict__ S,
                                                   float* __restrict__ out) {
    int row  = (int)((blockIdx.x * blockDim.x + threadIdx.x) >> 6);
    int lane = threadIdx.x & 63;
    int partner = (row < N_ROWS) ? row + N_ROWS : row - N_ROWS;
    ushort4 ah = ((const ushort4*)(Whi + (size_t)row * D))[lane];
    ushort4 al = ((const ushort4*)(Wlo + (size_t)row * D))[lane];
    ushort4 bh = ((const ushort4*)(Whi + (size_t)partner * D))[lane];
    ushort4 bl = ((const ushort4*)(Wlo + (size_t)partner * D))[lane];
    const unsigned short* ahp = (const unsigned short*)&ah;
    const unsigned short* alp = (const unsigned short*)&al;
    const unsigned short* bhp = (const unsigned short*)&bh;
    const unsigned short* blp = (const unsigned short*)&bl;
    float d = 0.f;
    #pragma unroll
    for (int i = 0; i < 4; ++i) {
        float a = bf2f(ahp[i]) + bf2f(alp[i]);
        float b = bf2f(bhp[i]) + bf2f(blp[i]);
        d = fmaf(a, b, d);
    }
    #pragma unroll
    for (int off = 32; off > 0; off >>= 1) d += __shfl_xor(d, off);
    if (lane == 0) out[row] = logf(S[row]) + 10.0f - 10.0f * d;
}

extern "C" void kernel_launch(void* const* d_in, const int* in_sizes, int n_in,
                              void* d_out, int out_size, void* d_ws, size_t ws_size,
                              hipStream_t stream) {
    const float* x1 = (const float*)d_in[0];
    const float* x2 = (const float*)d_in[1];
    float* out = (float*)d_out;

    unsigned short* Whi = (unsigned short*)d_ws;                    // 4 MB
    unsigned short* Wlo = Whi + (size_t)TWO_N * D;                  // 4 MB
    float* S = (float*)(Wlo + (size_t)TWO_N * D);                   // 32 KB

    normalize_k<<<TWO_N / 4, 256, 0, stream>>>(x1, x2, Whi, Wlo, S);
    nce_partial_k<<<NTRI, 256, 0, stream>>>(Whi, Wlo, S);
    nce_final_k<<<TWO_N / 4, 256, 0, stream>>>(Whi, Wlo, S, out);
}